// Round 1
// baseline (158.390 us; speedup 1.0000x reference)
//
#include <hip/hip_runtime.h>

// Problem constants
constexpr int NB  = 1024;   // batch
constexpr int NIN = 512;    // input features
constexpr int NJ  = 64;     // J
constexpr int NK  = 8;      // K
constexpr int NC  = NJ * NK;          // 512 output cols of M
constexpr int OUTC = NIN + NJ;        // 576
constexpr float EXPN10 = 4.5399929762484854e-05f;  // exp(-10)

// ---------------------------------------------------------------------------
// Kernel 1: M_perm[j][b][k] = sum_i x[b][i] * T[i][j*8+k]
// fp32 LDS-tiled GEMM: 64x64 tile, 256 threads, 4x4 micro-tile, BK=16.
// ---------------------------------------------------------------------------
__global__ __launch_bounds__(256) void gemm_kernel(const float* __restrict__ x,
                                                   const float* __restrict__ T,
                                                   float* __restrict__ Mp) {
  __shared__ __align__(16) float Xs[16][68];  // [kk][b-in-tile], pad 68 (16B-aligned rows)
  __shared__ __align__(16) float Ts[16][68];  // [kk][c-in-tile]

  const int tid = threadIdx.x;
  const int b0 = blockIdx.x * 64;   // b-tile base (16 tiles)
  const int c0 = blockIdx.y * 64;   // c-tile base (8 tiles)
  const int tx = tid & 15;          // 0..15 -> c micro
  const int ty = tid >> 4;          // 0..15 -> b micro

  // staging indices
  const int xr = tid >> 2;          // 0..63  row (b) within tile
  const int xi = (tid & 3) * 4;     // i offset within k-chunk
  const int tr = tid >> 4;          // 0..15  row (i) within k-chunk
  const int tc = (tid & 15) * 4;    // col offset

  float acc[4][4] = {};

  for (int k0 = 0; k0 < NIN; k0 += 16) {
    float4 xv = *(const float4*)&x[(b0 + xr) * NIN + k0 + xi];
    Xs[xi + 0][xr] = xv.x;
    Xs[xi + 1][xr] = xv.y;
    Xs[xi + 2][xr] = xv.z;
    Xs[xi + 3][xr] = xv.w;
    float4 tv = *(const float4*)&T[(k0 + tr) * NC + c0 + tc];
    *(float4*)&Ts[tr][tc] = tv;
    __syncthreads();

#pragma unroll
    for (int kk = 0; kk < 16; ++kk) {
      float4 xa = *(const float4*)&Xs[kk][ty * 4];
      float4 tb = *(const float4*)&Ts[kk][tx * 4];
      const float xs[4] = {xa.x, xa.y, xa.z, xa.w};
      const float ts[4] = {tb.x, tb.y, tb.z, tb.w};
#pragma unroll
      for (int r = 0; r < 4; ++r)
#pragma unroll
        for (int c = 0; c < 4; ++c)
          acc[r][c] = fmaf(xs[r], ts[c], acc[r][c]);
    }
    __syncthreads();
  }

  // write out permuted: Mp[j][b][k], c = j*8 + k
#pragma unroll
  for (int r = 0; r < 4; ++r) {
    const int b = b0 + ty * 4 + r;
#pragma unroll
    for (int c = 0; c < 4; ++c) {
      const int cc = c0 + tx * 4 + c;
      const int j = cc >> 3, k = cc & 7;
      Mp[(j * NB + b) * NK + k] = acc[r][c];
    }
  }
}

// ---------------------------------------------------------------------------
// Kernel 2: pairwise features.
// Block = (j, b-chunk of 128). 256 threads; each thread owns 4 a-vectors
// (a = tid + 256*r) in registers, iterates the 128-b LDS tile.
// c = exp(-min(norm,10)); norm>=10 for ~all pairs -> constant EXPN10, guarded
// by a wave-uniform __any so sqrt/exp almost never execute.
// ---------------------------------------------------------------------------
__global__ __launch_bounds__(256) void pairwise_kernel(const float* __restrict__ Mp,
                                                       float* __restrict__ feats) {
  const int j   = blockIdx.x;        // 0..63
  const int bc  = blockIdx.y;        // 0..7
  const int tid = threadIdx.x;       // 0..255
  const float* __restrict__ Mj = Mp + (size_t)j * NB * NK;

  __shared__ __align__(16) float Bs[128 * NK];  // 4 KB tile

  // Load 4 a-vectors into registers (32 VGPRs)
  float av[4][8];
#pragma unroll
  for (int r = 0; r < 4; ++r) {
    const float4 lo = *(const float4*)&Mj[(tid + 256 * r) * NK];
    const float4 hi = *(const float4*)&Mj[(tid + 256 * r) * NK + 4];
    av[r][0] = lo.x; av[r][1] = lo.y; av[r][2] = lo.z; av[r][3] = lo.w;
    av[r][4] = hi.x; av[r][5] = hi.y; av[r][6] = hi.z; av[r][7] = hi.w;
  }

  // Stage b-tile: 128*8 = 1024 floats, 256 threads x float4 (coalesced)
  const int bbase = bc * 128;
  *(float4*)&Bs[tid * 4] = *(const float4*)&Mj[bbase * NK + tid * 4];
  __syncthreads();

  float acc[4] = {0.f, 0.f, 0.f, 0.f};

#pragma unroll 2
  for (int bt = 0; bt < 128; ++bt) {
    float bv[8];
    *(float4*)&bv[0] = *(const float4*)&Bs[bt * NK];       // broadcast reads
    *(float4*)&bv[4] = *(const float4*)&Bs[bt * NK + 4];
#pragma unroll
    for (int r = 0; r < 4; ++r) {
      float sq = 0.f;
#pragma unroll
      for (int k = 0; k < NK; ++k) {
        const float d = av[r][k] - bv[k];
        sq = fmaf(d, d, sq);
      }
      float c = EXPN10;
      if (__any(sq < 100.0f)) {         // wave-uniform guard, almost never taken
        if (sq < 100.0f) c = __expf(-sqrtf(sq));
      }
      acc[r] += c;
    }
  }

#pragma unroll
  for (int r = 0; r < 4; ++r)
    atomicAdd(&feats[(tid + 256 * r) * NJ + j], acc[r]);
}

// ---------------------------------------------------------------------------
// Kernel 3: out[b][0:512] = x[b]; out[b][512:576] = feats[b]
// ---------------------------------------------------------------------------
__global__ __launch_bounds__(256) void out_kernel(const float* __restrict__ x,
                                                  const float* __restrict__ feats,
                                                  float* __restrict__ out) {
  const int idx = blockIdx.x * 256 + threadIdx.x;
  if (idx >= NB * OUTC) return;
  const int b = idx / OUTC;
  const int c = idx - b * OUTC;
  out[idx] = (c < NIN) ? x[b * NIN + c] : feats[b * NJ + (c - NIN)];
}

// ---------------------------------------------------------------------------
extern "C" void kernel_launch(void* const* d_in, const int* in_sizes, int n_in,
                              void* d_out, int out_size, void* d_ws, size_t ws_size,
                              hipStream_t stream) {
  const float* x = (const float*)d_in[0];   // [1024, 512]
  const float* T = (const float*)d_in[1];   // [512, 64, 8]
  float* out = (float*)d_out;               // [1024, 576]

  float* Mp    = (float*)d_ws;              // [64][1024][8] = 2 MB
  float* feats = Mp + (size_t)NJ * NB * NK; // [1024][64]    = 256 KB

  hipMemsetAsync(feats, 0, (size_t)NB * NJ * sizeof(float), stream);

  gemm_kernel<<<dim3(NB / 64, NC / 64), 256, 0, stream>>>(x, T, Mp);
  pairwise_kernel<<<dim3(NJ, NB / 128), 256, 0, stream>>>(Mp, feats);
  out_kernel<<<dim3((NB * OUTC + 255) / 256), 256, 0, stream>>>(x, feats, out);
}

// Round 2
// 147.713 us; speedup vs baseline: 1.0723x; 1.0723x over previous
//
#include <hip/hip_runtime.h>

// Problem constants
constexpr int NB  = 1024;   // batch
constexpr int NIN = 512;    // input features
constexpr int NJ  = 64;     // J
constexpr int NK  = 8;      // K
constexpr int NC  = NJ * NK;          // 512 output cols of M
constexpr int OUTC = NIN + NJ;        // 576
constexpr float EXPN10 = 4.5399929762484854e-05f;  // exp(-10)

// ---------------------------------------------------------------------------
// Kernel 1: M_perm[j][b][k] = sum_i x[b][i] * T[i][j*8+k]
// fp32 LDS-tiled GEMM: 64x64 tile, 256 threads, 4x4 micro-tile, BK=16.
// (128 blocks = half machine; acceptable for now, revisit if it tops profile)
// ---------------------------------------------------------------------------
__global__ __launch_bounds__(256) void gemm_kernel(const float* __restrict__ x,
                                                   const float* __restrict__ T,
                                                   float* __restrict__ Mp) {
  __shared__ __align__(16) float Xs[16][68];
  __shared__ __align__(16) float Ts[16][68];

  const int tid = threadIdx.x;
  const int b0 = blockIdx.x * 64;
  const int c0 = blockIdx.y * 64;
  const int tx = tid & 15;
  const int ty = tid >> 4;

  const int xr = tid >> 2;
  const int xi = (tid & 3) * 4;
  const int tr = tid >> 4;
  const int tc = (tid & 15) * 4;

  float acc[4][4] = {};

  for (int k0 = 0; k0 < NIN; k0 += 16) {
    float4 xv = *(const float4*)&x[(b0 + xr) * NIN + k0 + xi];
    Xs[xi + 0][xr] = xv.x;
    Xs[xi + 1][xr] = xv.y;
    Xs[xi + 2][xr] = xv.z;
    Xs[xi + 3][xr] = xv.w;
    float4 tv = *(const float4*)&T[(k0 + tr) * NC + c0 + tc];
    *(float4*)&Ts[tr][tc] = tv;
    __syncthreads();

#pragma unroll
    for (int kk = 0; kk < 16; ++kk) {
      float4 xa = *(const float4*)&Xs[kk][ty * 4];
      float4 tb = *(const float4*)&Ts[kk][tx * 4];
      const float xs[4] = {xa.x, xa.y, xa.z, xa.w};
      const float ts[4] = {tb.x, tb.y, tb.z, tb.w};
#pragma unroll
      for (int r = 0; r < 4; ++r)
#pragma unroll
        for (int c = 0; c < 4; ++c)
          acc[r][c] = fmaf(xs[r], ts[c], acc[r][c]);
    }
    __syncthreads();
  }

#pragma unroll
  for (int r = 0; r < 4; ++r) {
    const int b = b0 + ty * 4 + r;
#pragma unroll
    for (int c = 0; c < 4; ++c) {
      const int cc = c0 + tx * 4 + c;
      const int j = cc >> 3, k = cc & 7;
      Mp[(j * NB + b) * NK + k] = acc[r][c];
    }
  }
}

// ---------------------------------------------------------------------------
// Kernel 2: pairwise features, norm-expansion form.
//   d = a.b - (|a|^2+|b|^2)/2 = -sq/2 ;  sq < 100  <=>  d > -50
// Cheap path (≈100% of pairs): acc += exp(-10). Rare path (guarded by one
// wave-uniform __any per 4 pairs): exact diagonal c=1, else exp(-sqrt(sq)).
// 11 VALU/pair. Grid 64 j x 16 b-chunks = 1024 blocks (4/CU).
// ---------------------------------------------------------------------------
__global__ __launch_bounds__(256) void pairwise_kernel(const float* __restrict__ Mp,
                                                       float* __restrict__ feats) {
  const int j   = blockIdx.x;        // 0..63
  const int bc  = blockIdx.y;        // 0..15
  const int tid = threadIdx.x;       // 0..255
  const float* __restrict__ Mj = Mp + (size_t)j * NB * NK;

  __shared__ __align__(16) float Bs[64 * NK];  // 2 KB b-tile
  __shared__ float Hb[64];                     // -0.5*|b|^2

  // a-side: 4 vectors, a = r*256 + tid (coalesced float4 loads)
  float av[4][8], ha[4];
#pragma unroll
  for (int r = 0; r < 4; ++r) {
    const float4 lo = *(const float4*)&Mj[(r * 256 + tid) * NK];
    const float4 hi = *(const float4*)&Mj[(r * 256 + tid) * NK + 4];
    av[r][0] = lo.x; av[r][1] = lo.y; av[r][2] = lo.z; av[r][3] = lo.w;
    av[r][4] = hi.x; av[r][5] = hi.y; av[r][6] = hi.z; av[r][7] = hi.w;
    float s = 0.f;
#pragma unroll
    for (int k = 0; k < NK; ++k) s = fmaf(av[r][k], av[r][k], s);
    ha[r] = -0.5f * s;
  }

  // b-side staging: 64 threads each own one b-vector
  const int bbase = bc * 64;
  if (tid < 64) {
    const float4 lo = *(const float4*)&Mj[(bbase + tid) * NK];
    const float4 hi = *(const float4*)&Mj[(bbase + tid) * NK + 4];
    *(float4*)&Bs[tid * NK]     = lo;
    *(float4*)&Bs[tid * NK + 4] = hi;
    float s = lo.x*lo.x + lo.y*lo.y + lo.z*lo.z + lo.w*lo.w
            + hi.x*hi.x + hi.y*hi.y + hi.z*hi.z + hi.w*hi.w;
    Hb[tid] = -0.5f * s;
  }
  __syncthreads();

  float acc[4] = {0.f, 0.f, 0.f, 0.f};

#pragma unroll 2
  for (int bt = 0; bt < 64; ++bt) {
    const float4 b0 = *(const float4*)&Bs[bt * NK];      // broadcast
    const float4 b1 = *(const float4*)&Bs[bt * NK + 4];
    const float hb = Hb[bt];
    const float bv[8] = {b0.x, b0.y, b0.z, b0.w, b1.x, b1.y, b1.z, b1.w};

    float d[4];
#pragma unroll
    for (int r = 0; r < 4; ++r) {
      float t = ha[r] + hb;
#pragma unroll
      for (int k = 0; k < NK; ++k) t = fmaf(av[r][k], bv[k], t);
      d[r] = t;
      acc[r] += EXPN10;
    }

    const float dm = fmaxf(fmaxf(d[0], d[1]), fmaxf(d[2], d[3]));
    if (__any(dm > -50.0f)) {        // wave-uniform, rare
#pragma unroll
      for (int r = 0; r < 4; ++r) {
        if (d[r] > -50.0f) {
          const int a = r * 256 + tid;
          const int b = bbase + bt;
          const float sq = fmaxf(-2.0f * d[r], 0.0f);
          const float c = (a == b) ? 1.0f : __expf(-sqrtf(sq));
          acc[r] += c - EXPN10;
        }
      }
    }
  }

#pragma unroll
  for (int r = 0; r < 4; ++r)
    atomicAdd(&feats[(r * 256 + tid) * NJ + j], acc[r]);
}

// ---------------------------------------------------------------------------
// Kernel 3: out[b][0:512] = x[b]; out[b][512:576] = feats[b]
// ---------------------------------------------------------------------------
__global__ __launch_bounds__(256) void out_kernel(const float* __restrict__ x,
                                                  const float* __restrict__ feats,
                                                  float* __restrict__ out) {
  const int idx = blockIdx.x * 256 + threadIdx.x;
  if (idx >= NB * OUTC) return;
  const int b = idx / OUTC;
  const int c = idx - b * OUTC;
  out[idx] = (c < NIN) ? x[b * NIN + c] : feats[b * NJ + (c - NIN)];
}

// ---------------------------------------------------------------------------
extern "C" void kernel_launch(void* const* d_in, const int* in_sizes, int n_in,
                              void* d_out, int out_size, void* d_ws, size_t ws_size,
                              hipStream_t stream) {
  const float* x = (const float*)d_in[0];   // [1024, 512]
  const float* T = (const float*)d_in[1];   // [512, 64, 8]
  float* out = (float*)d_out;               // [1024, 576]

  float* Mp    = (float*)d_ws;              // [64][1024][8] = 2 MB
  float* feats = Mp + (size_t)NJ * NB * NK; // [1024][64]    = 256 KB

  hipMemsetAsync(feats, 0, (size_t)NB * NJ * sizeof(float), stream);

  gemm_kernel<<<dim3(NB / 64, NC / 64), 256, 0, stream>>>(x, T, Mp);
  pairwise_kernel<<<dim3(NJ, 16), 256, 0, stream>>>(Mp, feats);
  out_kernel<<<dim3((NB * OUTC + 255) / 256), 256, 0, stream>>>(x, feats, out);
}